// Round 5
// baseline (441.151 us; speedup 1.0000x reference)
//
#include <hip/hip_runtime.h>
#include <hip/hip_bf16.h>

// InfoNCE loss, B=4096 D=768 N=8192, T=0.5, fp32 in, fp32 scalar out.
// R5: MX-fp8 with 32x32x64 mfma_scale (unity scales), BKB=64 (12 k-iters,
// 16 KB LDS), __launch_bounds__(256,4) to force >=4 resident blocks/CU.
// R4's 16x16x128 held 8 B-frags live (64 VGPR) -> 160 VGPR, 1 block/CU,
// barrier-stalled. 32x32x64 needs only 4 B-frags.

#define B_SZ 4096
#define D_SZ 768
#define N_SZ 8192
constexpr float INV_T = 2.0f;  // 1/temperature

typedef float f32x16 __attribute__((ext_vector_type(16)));
typedef int i32x8 __attribute__((ext_vector_type(8)));
typedef __attribute__((address_space(1))) const unsigned int gu32;
typedef __attribute__((address_space(3))) unsigned int lu32;

__device__ inline void async16(const void* g, void* l) {
    // per-lane global addr, wave-uniform LDS base; lane i lands at base + i*16.
    __builtin_amdgcn_global_load_lds((gu32*)g, (lu32*)l, 16, 0, 0);
}

// ---- 1) fused prep: norms + positives + e4m3 rows + rowsum zeroing ----
// One wave per pair, float4 loads, packed fp8 dword stores.
__global__ __launch_bounds__(256) void prep_k(const float* __restrict__ h1,
                                              const float* __restrict__ h2,
                                              unsigned char* __restrict__ hn8,
                                              float* __restrict__ pos,
                                              float* __restrict__ rowsum) {
    const int i = blockIdx.x * 4 + (threadIdx.x >> 6);
    const int lane = threadIdx.x & 63;
    const float4* a4 = (const float4*)(h1 + (size_t)i * D_SZ);
    const float4* b4 = (const float4*)(h2 + (size_t)i * D_SZ);
    float4 av[3], bv[3];
    float sa = 0.f, sb = 0.f, dt = 0.f;
#pragma unroll
    for (int j = 0; j < 3; ++j) {
        av[j] = a4[lane + j * 64];
        bv[j] = b4[lane + j * 64];
        sa += av[j].x * av[j].x + av[j].y * av[j].y + av[j].z * av[j].z + av[j].w * av[j].w;
        sb += bv[j].x * bv[j].x + bv[j].y * bv[j].y + bv[j].z * bv[j].z + bv[j].w * bv[j].w;
        dt += av[j].x * bv[j].x + av[j].y * bv[j].y + av[j].z * bv[j].z + av[j].w * bv[j].w;
    }
#pragma unroll
    for (int m = 1; m < 64; m <<= 1) {
        sa += __shfl_xor(sa, m, 64);
        sb += __shfl_xor(sb, m, 64);
        dt += __shfl_xor(dt, m, 64);
    }
    const float n1 = fmaxf(sqrtf(sa), 1e-8f), n2 = fmaxf(sqrtf(sb), 1e-8f);
    const float i1 = 1.0f / n1, i2 = 1.0f / n2;
    unsigned int* d1 = (unsigned int*)(hn8 + (size_t)i * D_SZ);
    unsigned int* d2 = (unsigned int*)(hn8 + (size_t)(i + B_SZ) * D_SZ);
#pragma unroll
    for (int j = 0; j < 3; ++j) {
        unsigned int u1 = __builtin_amdgcn_cvt_pk_fp8_f32(av[j].x * i1, av[j].y * i1, 0, false);
        u1 = __builtin_amdgcn_cvt_pk_fp8_f32(av[j].z * i1, av[j].w * i1, u1, true);
        unsigned int u2 = __builtin_amdgcn_cvt_pk_fp8_f32(bv[j].x * i2, bv[j].y * i2, 0, false);
        u2 = __builtin_amdgcn_cvt_pk_fp8_f32(bv[j].z * i2, bv[j].w * i2, u2, true);
        d1[lane + j * 64] = u1;
        d2[lane + j * 64] = u2;
    }
    if (lane == 0) {
        float p = dt * i1 * i2 * INV_T;
        pos[i] = p;
        pos[i + B_SZ] = p;
        rowsum[i] = 0.f;  // ws re-poisoned each call; zero here
        rowsum[i + B_SZ] = 0.f;
    }
}

// ---- 2) symmetric fused sim-GEMM (MX-fp8, 32x32x64) + exp-rowsum ----
// 128x128 tile, 4 waves, each wave one 32-row m-strip x 128 cols (4 n-tiles).
// Unpadded LDS rows of 64 B: global_load_lds w16 lands lane l at row l>>2,
// chunk l&3. Waves 0-1 stage A, waves 2-3 stage B (4 async16 each / iter).
#define BM 128
#define BN 128
#define BKB 64  // fp8 bytes along K per iter

__global__ __launch_bounds__(256, 4) void gemm_reduce_k(const unsigned char* __restrict__ hn8,
                                                        float* __restrict__ rowsum) {
    __shared__ __align__(16) unsigned char As[BM * BKB];  // 8 KB
    __shared__ __align__(16) unsigned char Bs[BN * BKB];  // 8 KB
    // triangular index -> (ty, tx), ty <= tx
    const int b = blockIdx.x;
    int tx = (int)((sqrtf(8.0f * (float)b + 1.0f) - 1.0f) * 0.5f);
    while ((tx + 1) * (tx + 2) / 2 <= b) ++tx;
    while (tx * (tx + 1) / 2 > b) --tx;
    const int ty = b - tx * (tx + 1) / 2;
    const int rowBase = ty * BM;
    const int colBase = tx * BN;
    const bool diagBlk = (ty == tx);

    const int tid = threadIdx.x;
    const int wave = tid >> 6;
    const int lane = tid & 63;
    const int l32 = lane & 31;
    const int half = lane >> 5;

    f32x16 acc[4];
#pragma unroll
    for (int nt = 0; nt < 4; ++nt)
#pragma unroll
        for (int j = 0; j < 16; ++j) acc[nt][j] = 0.f;

    // staging: waves 0-1 -> A rows (wave*64..), waves 2-3 -> B rows ((wave-2)*64..)
    const bool stageB = wave >= 2;
    const int rbase = (wave & 1) * 64 + (lane >> 2);
    const unsigned char* gsrc =
        hn8 + (size_t)((stageB ? colBase : rowBase) + rbase) * D_SZ + (lane & 3) * 16;
    unsigned char* ldst = (stageB ? Bs : As) + (wave & 1) * 64 * BKB;

    for (int k0 = 0; k0 < D_SZ; k0 += BKB) {
        __syncthreads();
#pragma unroll
        for (int t = 0; t < 4; ++t)
            async16(gsrc + k0 + (size_t)t * 16 * D_SZ, ldst + t * 16 * BKB);
        __syncthreads();

        // A-frag: lane holds A[m=l32][k=half*32+j], 32 contiguous bytes.
        i32x8 a = *(const i32x8*)&As[(wave * 32 + l32) * BKB + half * 32];
#pragma unroll
        for (int nt = 0; nt < 4; ++nt) {
            i32x8 bf = *(const i32x8*)&Bs[(nt * 32 + l32) * BKB + half * 32];
            acc[nt] = __builtin_amdgcn_mfma_scale_f32_32x32x64_f8f6f4(
                a, bf, acc[nt], 0, 0, 0, 0x7F7F7F7F, 0, 0x7F7F7F7F);
        }
    }

    // epilogue: 32x32 C/D layout col=l32, row=(j&3)+8*(j>>2)+4*half.
    // exp once -> row sums (regs) + col sums (symmetry) for off-diag blocks.
    float rs[16];
#pragma unroll
    for (int j = 0; j < 16; ++j) rs[j] = 0.f;
#pragma unroll
    for (int nt = 0; nt < 4; ++nt) {
        const int col = colBase + nt * 32 + l32;
        float cs = 0.f;
#pragma unroll
        for (int j = 0; j < 16; ++j) {
            int row = rowBase + wave * 32 + (j & 3) + 8 * (j >> 2) + 4 * half;
            float e = __expf(acc[nt][j] * INV_T);
            e = (diagBlk && row == col) ? 0.f : e;
            rs[j] += e;
            cs += e;
        }
        if (!diagBlk) {
            cs += __shfl_xor(cs, 32, 64);
            if (half == 0) atomicAdd(&rowsum[col], cs);
        }
    }
#pragma unroll
    for (int j = 0; j < 16; ++j) {
        float s = rs[j];
#pragma unroll
        for (int m = 1; m < 32; m <<= 1) s += __shfl_xor(s, m, 64);
        if (l32 == 0)
            atomicAdd(&rowsum[rowBase + wave * 32 + (j & 3) + 8 * (j >> 2) + 4 * half], s);
    }
}

// ---- 3) loss = mean(log(rowsum) - pos), 1024 threads, float4 loads ----
__global__ __launch_bounds__(1024) void finalize_k(const float* __restrict__ rowsum,
                                                   const float* __restrict__ pos,
                                                   float* __restrict__ out) {
    __shared__ float red[16];
    const int t = threadIdx.x;
    const float4* rs4 = (const float4*)rowsum;
    const float4* ps4 = (const float4*)pos;
    float s = 0.f;
#pragma unroll
    for (int j = 0; j < 2; ++j) {
        float4 r = rs4[t * 2 + j];
        float4 p = ps4[t * 2 + j];
        s += (__logf(r.x) - p.x) + (__logf(r.y) - p.y) +
             (__logf(r.z) - p.z) + (__logf(r.w) - p.w);
    }
#pragma unroll
    for (int m = 1; m < 64; m <<= 1) s += __shfl_xor(s, m, 64);
    if ((t & 63) == 0) red[t >> 6] = s;
    __syncthreads();
    if (t == 0) {
        float tot = 0.f;
#pragma unroll
        for (int w = 0; w < 16; ++w) tot += red[w];
        out[0] = tot * (1.0f / (float)N_SZ);
    }
}

extern "C" void kernel_launch(void* const* d_in, const int* in_sizes, int n_in,
                              void* d_out, int out_size, void* d_ws, size_t ws_size,
                              hipStream_t stream) {
    const float* h1 = (const float*)d_in[0];
    const float* h2 = (const float*)d_in[1];
    float* out = (float*)d_out;

    char* ws = (char*)d_ws;
    unsigned char* hn8 = (unsigned char*)ws;                      // N*D = 6,291,456 B
    float* pos    = (float*)(ws + (size_t)N_SZ * D_SZ);            // 32 KB
    float* rowsum = (float*)(ws + (size_t)N_SZ * D_SZ + 32768);    // 32 KB

    prep_k<<<B_SZ / 4, 256, 0, stream>>>(h1, h2, hn8, pos, rowsum);
    const int nTiles = N_SZ / BN;                    // 64
    const int nBlocks = nTiles * (nTiles + 1) / 2;   // 2080
    gemm_reduce_k<<<nBlocks, 256, 0, stream>>>(hn8, rowsum);
    finalize_k<<<1, 1024, 0, stream>>>(rowsum, pos, out);
}

// Round 6
// 297.009 us; speedup vs baseline: 1.4853x; 1.4853x over previous
//
#include <hip/hip_runtime.h>
#include <hip/hip_bf16.h>

// InfoNCE loss, B=4096 D=768 N=8192, T=0.5, fp32 in, fp32 scalar out.
// R6: R5 (MX-fp8 32x32x64, BKB=64) with two fixes:
//  - launch_bounds(256,3): R5's (256,4) = 128-VGPR cap made the compiler SPILL
//    the 64-VGPR accumulator to scratch (WRITE_SIZE 8->667 MB, 389 us).
//  - XOR chunk swizzle on LDS: lane l fetches global chunk (l&3)^((l>>3)&3) so
//    logical chunk c of row r sits at position c^((r>>1)&3); read banks then
//    cover all 32 (R5 pattern could only reach 16 -> structural 2x LDS cost).

#define B_SZ 4096
#define D_SZ 768
#define N_SZ 8192
constexpr float INV_T = 2.0f;  // 1/temperature

typedef float f32x16 __attribute__((ext_vector_type(16)));
typedef int i32x8 __attribute__((ext_vector_type(8)));
typedef int i32x4 __attribute__((ext_vector_type(4)));
typedef __attribute__((address_space(1))) const unsigned int gu32;
typedef __attribute__((address_space(3))) unsigned int lu32;

__device__ inline void async16(const void* g, void* l) {
    // per-lane global addr, wave-uniform LDS base; lane i lands at base + i*16.
    __builtin_amdgcn_global_load_lds((gu32*)g, (lu32*)l, 16, 0, 0);
}

// ---- 1) fused prep: norms + positives + e4m3 rows + rowsum zeroing ----
__global__ __launch_bounds__(256) void prep_k(const float* __restrict__ h1,
                                              const float* __restrict__ h2,
                                              unsigned char* __restrict__ hn8,
                                              float* __restrict__ pos,
                                              float* __restrict__ rowsum) {
    const int i = blockIdx.x * 4 + (threadIdx.x >> 6);
    const int lane = threadIdx.x & 63;
    const float4* a4 = (const float4*)(h1 + (size_t)i * D_SZ);
    const float4* b4 = (const float4*)(h2 + (size_t)i * D_SZ);
    float4 av[3], bv[3];
    float sa = 0.f, sb = 0.f, dt = 0.f;
#pragma unroll
    for (int j = 0; j < 3; ++j) {
        av[j] = a4[lane + j * 64];
        bv[j] = b4[lane + j * 64];
        sa += av[j].x * av[j].x + av[j].y * av[j].y + av[j].z * av[j].z + av[j].w * av[j].w;
        sb += bv[j].x * bv[j].x + bv[j].y * bv[j].y + bv[j].z * bv[j].z + bv[j].w * bv[j].w;
        dt += av[j].x * bv[j].x + av[j].y * bv[j].y + av[j].z * bv[j].z + av[j].w * bv[j].w;
    }
#pragma unroll
    for (int m = 1; m < 64; m <<= 1) {
        sa += __shfl_xor(sa, m, 64);
        sb += __shfl_xor(sb, m, 64);
        dt += __shfl_xor(dt, m, 64);
    }
    const float n1 = fmaxf(sqrtf(sa), 1e-8f), n2 = fmaxf(sqrtf(sb), 1e-8f);
    const float i1 = 1.0f / n1, i2 = 1.0f / n2;
    unsigned int* d1 = (unsigned int*)(hn8 + (size_t)i * D_SZ);
    unsigned int* d2 = (unsigned int*)(hn8 + (size_t)(i + B_SZ) * D_SZ);
#pragma unroll
    for (int j = 0; j < 3; ++j) {
        unsigned int u1 = __builtin_amdgcn_cvt_pk_fp8_f32(av[j].x * i1, av[j].y * i1, 0, false);
        u1 = __builtin_amdgcn_cvt_pk_fp8_f32(av[j].z * i1, av[j].w * i1, u1, true);
        unsigned int u2 = __builtin_amdgcn_cvt_pk_fp8_f32(bv[j].x * i2, bv[j].y * i2, 0, false);
        u2 = __builtin_amdgcn_cvt_pk_fp8_f32(bv[j].z * i2, bv[j].w * i2, u2, true);
        d1[lane + j * 64] = u1;
        d2[lane + j * 64] = u2;
    }
    if (lane == 0) {
        float p = dt * i1 * i2 * INV_T;
        pos[i] = p;
        pos[i + B_SZ] = p;
        rowsum[i] = 0.f;  // ws re-poisoned each call; zero here
        rowsum[i + B_SZ] = 0.f;
    }
}

// ---- 2) symmetric fused sim-GEMM (MX-fp8, 32x32x64) + exp-rowsum ----
// 128x128 tile, 4 waves, each wave one 32-row m-strip x 128 cols (4 n-tiles).
// Unpadded 64 B LDS rows for global_load_lds w16; chunk-XOR swizzle for banks.
#define BM 128
#define BN 128
#define BKB 64  // fp8 bytes along K per iter

__global__ __launch_bounds__(256, 3) void gemm_reduce_k(const unsigned char* __restrict__ hn8,
                                                        float* __restrict__ rowsum) {
    __shared__ __align__(16) unsigned char As[BM * BKB];  // 8 KB
    __shared__ __align__(16) unsigned char Bs[BN * BKB];  // 8 KB
    // triangular index -> (ty, tx), ty <= tx
    const int b = blockIdx.x;
    int tx = (int)((sqrtf(8.0f * (float)b + 1.0f) - 1.0f) * 0.5f);
    while ((tx + 1) * (tx + 2) / 2 <= b) ++tx;
    while (tx * (tx + 1) / 2 > b) --tx;
    const int ty = b - tx * (tx + 1) / 2;
    const int rowBase = ty * BM;
    const int colBase = tx * BN;
    const bool diagBlk = (ty == tx);

    const int tid = threadIdx.x;
    const int wave = tid >> 6;
    const int lane = tid & 63;
    const int l32 = lane & 31;
    const int half = lane >> 5;

    f32x16 acc[4];
#pragma unroll
    for (int nt = 0; nt < 4; ++nt)
#pragma unroll
        for (int j = 0; j < 16; ++j) acc[nt][j] = 0.f;

    // staging: waves 0-1 -> A rows, waves 2-3 -> B rows. Lane l fetches global
    // chunk (l&3)^((l>>3)&3) so logical chunk c of row r lands at c^((r>>1)&3).
    const bool stageB = wave >= 2;
    const int lr = lane >> 2;
    const int cg = (lane & 3) ^ ((lane >> 3) & 3);
    const unsigned char* gsrc =
        hn8 + (size_t)((stageB ? colBase : rowBase) + (wave & 1) * 64 + lr) * D_SZ + cg * 16;
    unsigned char* ldst = (stageB ? Bs : As) + (wave & 1) * 64 * BKB;

    // LDS read addresses (constant across k): logical chunk 2*half at p0, +1 at p0^1.
    const int sz = (l32 >> 1) & 3;
    const int p0 = (2 * half) ^ sz;
    const int p1 = p0 ^ 1;
    const unsigned char* aLo = &As[(wave * 32 + l32) * BKB + p0 * 16];
    const unsigned char* aHi = &As[(wave * 32 + l32) * BKB + p1 * 16];
    const unsigned char* bLo = &Bs[l32 * BKB + p0 * 16];
    const unsigned char* bHi = &Bs[l32 * BKB + p1 * 16];

    for (int k0 = 0; k0 < D_SZ; k0 += BKB) {
        __syncthreads();
#pragma unroll
        for (int t = 0; t < 4; ++t)
            async16(gsrc + k0 + (size_t)t * 16 * D_SZ, ldst + t * 16 * BKB);
        __syncthreads();

        i32x4 alo = *(const i32x4*)aLo;
        i32x4 ahi = *(const i32x4*)aHi;
        i32x8 a = {alo[0], alo[1], alo[2], alo[3], ahi[0], ahi[1], ahi[2], ahi[3]};
#pragma unroll
        for (int nt = 0; nt < 4; ++nt) {
            i32x4 blo = *(const i32x4*)(bLo + nt * 32 * BKB);
            i32x4 bhi = *(const i32x4*)(bHi + nt * 32 * BKB);
            i32x8 bf = {blo[0], blo[1], blo[2], blo[3], bhi[0], bhi[1], bhi[2], bhi[3]};
            acc[nt] = __builtin_amdgcn_mfma_scale_f32_32x32x64_f8f6f4(
                a, bf, acc[nt], 0, 0, 0, 0x7F7F7F7F, 0, 0x7F7F7F7F);
        }
    }

    // epilogue: 32x32 C/D layout col=l32, row=(j&3)+8*(j>>2)+4*half (verified R5).
    float rs[16];
#pragma unroll
    for (int j = 0; j < 16; ++j) rs[j] = 0.f;
#pragma unroll
    for (int nt = 0; nt < 4; ++nt) {
        const int col = colBase + nt * 32 + l32;
        float cs = 0.f;
#pragma unroll
        for (int j = 0; j < 16; ++j) {
            int row = rowBase + wave * 32 + (j & 3) + 8 * (j >> 2) + 4 * half;
            float e = __expf(acc[nt][j] * INV_T);
            e = (diagBlk && row == col) ? 0.f : e;
            rs[j] += e;
            cs += e;
        }
        if (!diagBlk) {
            cs += __shfl_xor(cs, 32, 64);
            if (half == 0) atomicAdd(&rowsum[col], cs);
        }
    }
#pragma unroll
    for (int j = 0; j < 16; ++j) {
        float s = rs[j];
#pragma unroll
        for (int m = 1; m < 32; m <<= 1) s += __shfl_xor(s, m, 64);
        if (l32 == 0)
            atomicAdd(&rowsum[rowBase + wave * 32 + (j & 3) + 8 * (j >> 2) + 4 * half], s);
    }
}

// ---- 3) loss = mean(log(rowsum) - pos), 1024 threads, float4 loads ----
__global__ __launch_bounds__(1024) void finalize_k(const float* __restrict__ rowsum,
                                                   const float* __restrict__ pos,
                                                   float* __restrict__ out) {
    __shared__ float red[16];
    const int t = threadIdx.x;
    const float4* rs4 = (const float4*)rowsum;
    const float4* ps4 = (const float4*)pos;
    float s = 0.f;
#pragma unroll
    for (int j = 0; j < 2; ++j) {
        float4 r = rs4[t * 2 + j];
        float4 p = ps4[t * 2 + j];
        s += (__logf(r.x) - p.x) + (__logf(r.y) - p.y) +
             (__logf(r.z) - p.z) + (__logf(r.w) - p.w);
    }
#pragma unroll
    for (int m = 1; m < 64; m <<= 1) s += __shfl_xor(s, m, 64);
    if ((t & 63) == 0) red[t >> 6] = s;
    __syncthreads();
    if (t == 0) {
        float tot = 0.f;
#pragma unroll
        for (int w = 0; w < 16; ++w) tot += red[w];
        out[0] = tot * (1.0f / (float)N_SZ);
    }
}

extern "C" void kernel_launch(void* const* d_in, const int* in_sizes, int n_in,
                              void* d_out, int out_size, void* d_ws, size_t ws_size,
                              hipStream_t stream) {
    const float* h1 = (const float*)d_in[0];
    const float* h2 = (const float*)d_in[1];
    float* out = (float*)d_out;

    char* ws = (char*)d_ws;
    unsigned char* hn8 = (unsigned char*)ws;                      // N*D = 6,291,456 B
    float* pos    = (float*)(ws + (size_t)N_SZ * D_SZ);            // 32 KB
    float* rowsum = (float*)(ws + (size_t)N_SZ * D_SZ + 32768);    // 32 KB

    prep_k<<<B_SZ / 4, 256, 0, stream>>>(h1, h2, hn8, pos, rowsum);
    const int nTiles = N_SZ / BN;                    // 64
    const int nBlocks = nTiles * (nTiles + 1) / 2;   // 2080
    gemm_reduce_k<<<nBlocks, 256, 0, stream>>>(hn8, rowsum);
    finalize_k<<<1, 1024, 0, stream>>>(rowsum, pos, out);
}

// Round 7
// 131.522 us; speedup vs baseline: 3.3542x; 2.2582x over previous
//
#include <hip/hip_runtime.h>
#include <hip/hip_bf16.h>

// InfoNCE loss, B=4096 D=768 N=8192, T=0.5, fp32 in, fp32 scalar out.
// R7: MX-fp8 32x32x64, 128x128 tile, 512-thread blocks (8 waves): each wave
// owns a 32x64 C-chunk -> acc is only 2x f32x16 = 32 VGPR. NO second
// launch_bounds arg: HW wave slots step at vgpr={64,128,256}, so (256,3)
// rounded to a 128-cap and spilled acc to scratch (R5/R6: 540 MB WRITE_SIZE).
// Keep the XOR chunk swizzle (conflicts 1.2e7 -> 4.0e6 verified R6).

#define B_SZ 4096
#define D_SZ 768
#define N_SZ 8192
constexpr float INV_T = 2.0f;  // 1/temperature

typedef float f32x16 __attribute__((ext_vector_type(16)));
typedef int i32x8 __attribute__((ext_vector_type(8)));
typedef int i32x4 __attribute__((ext_vector_type(4)));
typedef __attribute__((address_space(1))) const unsigned int gu32;
typedef __attribute__((address_space(3))) unsigned int lu32;

__device__ inline void async16(const void* g, void* l) {
    // per-lane global addr, wave-uniform LDS base; lane i lands at base + i*16.
    __builtin_amdgcn_global_load_lds((gu32*)g, (lu32*)l, 16, 0, 0);
}

// ---- 1) fused prep: norms + positives + e4m3 rows + rowsum zeroing ----
__global__ __launch_bounds__(256) void prep_k(const float* __restrict__ h1,
                                              const float* __restrict__ h2,
                                              unsigned char* __restrict__ hn8,
                                              float* __restrict__ pos,
                                              float* __restrict__ rowsum) {
    const int i = blockIdx.x * 4 + (threadIdx.x >> 6);
    const int lane = threadIdx.x & 63;
    const float4* a4 = (const float4*)(h1 + (size_t)i * D_SZ);
    const float4* b4 = (const float4*)(h2 + (size_t)i * D_SZ);
    float4 av[3], bv[3];
    float sa = 0.f, sb = 0.f, dt = 0.f;
#pragma unroll
    for (int j = 0; j < 3; ++j) {
        av[j] = a4[lane + j * 64];
        bv[j] = b4[lane + j * 64];
        sa += av[j].x * av[j].x + av[j].y * av[j].y + av[j].z * av[j].z + av[j].w * av[j].w;
        sb += bv[j].x * bv[j].x + bv[j].y * bv[j].y + bv[j].z * bv[j].z + bv[j].w * bv[j].w;
        dt += av[j].x * bv[j].x + av[j].y * bv[j].y + av[j].z * bv[j].z + av[j].w * bv[j].w;
    }
#pragma unroll
    for (int m = 1; m < 64; m <<= 1) {
        sa += __shfl_xor(sa, m, 64);
        sb += __shfl_xor(sb, m, 64);
        dt += __shfl_xor(dt, m, 64);
    }
    const float n1 = fmaxf(sqrtf(sa), 1e-8f), n2 = fmaxf(sqrtf(sb), 1e-8f);
    const float i1 = 1.0f / n1, i2 = 1.0f / n2;
    unsigned int* d1 = (unsigned int*)(hn8 + (size_t)i * D_SZ);
    unsigned int* d2 = (unsigned int*)(hn8 + (size_t)(i + B_SZ) * D_SZ);
#pragma unroll
    for (int j = 0; j < 3; ++j) {
        unsigned int u1 = __builtin_amdgcn_cvt_pk_fp8_f32(av[j].x * i1, av[j].y * i1, 0, false);
        u1 = __builtin_amdgcn_cvt_pk_fp8_f32(av[j].z * i1, av[j].w * i1, u1, true);
        unsigned int u2 = __builtin_amdgcn_cvt_pk_fp8_f32(bv[j].x * i2, bv[j].y * i2, 0, false);
        u2 = __builtin_amdgcn_cvt_pk_fp8_f32(bv[j].z * i2, bv[j].w * i2, u2, true);
        d1[lane + j * 64] = u1;
        d2[lane + j * 64] = u2;
    }
    if (lane == 0) {
        float p = dt * i1 * i2 * INV_T;
        pos[i] = p;
        pos[i + B_SZ] = p;
        rowsum[i] = 0.f;  // ws re-poisoned each call; zero here
        rowsum[i + B_SZ] = 0.f;
    }
}

// ---- 2) symmetric fused sim-GEMM (MX-fp8, 32x32x64) + exp-rowsum ----
// 128x128 tile, 8 waves: wave w computes m-strip (w&3)*32 x n-half (w>>2)*64.
// Unpadded 64 B LDS rows for global_load_lds w16; chunk-XOR swizzle for banks.
#define BM 128
#define BN 128
#define BKB 64  // fp8 bytes along K per iter

__global__ __launch_bounds__(512) void gemm_reduce_k(const unsigned char* __restrict__ hn8,
                                                     float* __restrict__ rowsum) {
    __shared__ __align__(16) unsigned char As[BM * BKB];  // 8 KB
    __shared__ __align__(16) unsigned char Bs[BN * BKB];  // 8 KB
    // triangular index -> (ty, tx), ty <= tx
    const int b = blockIdx.x;
    int tx = (int)((sqrtf(8.0f * (float)b + 1.0f) - 1.0f) * 0.5f);
    while ((tx + 1) * (tx + 2) / 2 <= b) ++tx;
    while (tx * (tx + 1) / 2 > b) --tx;
    const int ty = b - tx * (tx + 1) / 2;
    const int rowBase = ty * BM;
    const int colBase = tx * BN;
    const bool diagBlk = (ty == tx);

    const int tid = threadIdx.x;
    const int wave = tid >> 6;   // 0..7
    const int lane = tid & 63;
    const int l32 = lane & 31;
    const int half = lane >> 5;
    const int ms = wave & 3;     // m-strip (32 rows)
    const int nh = wave >> 2;    // n-half (64 cols)

    f32x16 acc[2];
#pragma unroll
    for (int nt = 0; nt < 2; ++nt)
#pragma unroll
        for (int j = 0; j < 16; ++j) acc[nt][j] = 0.f;

    // staging: waves 0-3 stage A strip (wave&3), waves 4-7 stage B strip (wave&3).
    // Lane l fetches global chunk (l&3)^((l>>3)&3) of row (l>>2); 2 instr/iter.
    const bool stB = wave >= 4;
    const int lr = lane >> 2;
    const int cg = (lane & 3) ^ ((lane >> 3) & 3);
    const unsigned char* gsrc =
        hn8 + (size_t)((stB ? colBase : rowBase) + ms * 32 + lr) * D_SZ + cg * 16;
    unsigned char* ldst = (stB ? Bs : As) + ms * 32 * BKB;

    // LDS read addrs (k-invariant): logical chunk c of row r sits at c^((r>>1)&3).
    const int sz = (l32 >> 1) & 3;
    const int p0 = (2 * half) ^ sz;
    const int p1 = p0 ^ 1;
    const unsigned char* aLo = &As[(ms * 32 + l32) * BKB + p0 * 16];
    const unsigned char* aHi = &As[(ms * 32 + l32) * BKB + p1 * 16];
    const unsigned char* bLo = &Bs[(nh * 64 + l32) * BKB + p0 * 16];
    const unsigned char* bHi = &Bs[(nh * 64 + l32) * BKB + p1 * 16];

    for (int k0 = 0; k0 < D_SZ; k0 += BKB) {
        __syncthreads();
        async16(gsrc + k0, ldst);
        async16(gsrc + k0 + (size_t)16 * D_SZ, ldst + 16 * BKB);
        __syncthreads();

        i32x4 alo = *(const i32x4*)aLo;
        i32x4 ahi = *(const i32x4*)aHi;
        i32x8 a = {alo[0], alo[1], alo[2], alo[3], ahi[0], ahi[1], ahi[2], ahi[3]};
#pragma unroll
        for (int nt = 0; nt < 2; ++nt) {
            i32x4 blo = *(const i32x4*)(bLo + nt * 32 * BKB);
            i32x4 bhi = *(const i32x4*)(bHi + nt * 32 * BKB);
            i32x8 bf = {blo[0], blo[1], blo[2], blo[3], bhi[0], bhi[1], bhi[2], bhi[3]};
            acc[nt] = __builtin_amdgcn_mfma_scale_f32_32x32x64_f8f6f4(
                a, bf, acc[nt], 0, 0, 0, 0x7F7F7F7F, 0, 0x7F7F7F7F);
        }
    }

    // epilogue: 32x32 C/D layout col=l32, row=(j&3)+8*(j>>2)+4*half (verified).
    float rs[16];
#pragma unroll
    for (int j = 0; j < 16; ++j) rs[j] = 0.f;
#pragma unroll
    for (int nt = 0; nt < 2; ++nt) {
        const int col = colBase + nh * 64 + nt * 32 + l32;
        float cs = 0.f;
#pragma unroll
        for (int j = 0; j < 16; ++j) {
            int row = rowBase + ms * 32 + (j & 3) + 8 * (j >> 2) + 4 * half;
            float e = __expf(acc[nt][j] * INV_T);
            e = (diagBlk && row == col) ? 0.f : e;
            rs[j] += e;
            cs += e;
        }
        if (!diagBlk) {
            cs += __shfl_xor(cs, 32, 64);
            if (half == 0) atomicAdd(&rowsum[col], cs);
        }
    }
#pragma unroll
    for (int j = 0; j < 16; ++j) {
        float s = rs[j];
#pragma unroll
        for (int m = 1; m < 32; m <<= 1) s += __shfl_xor(s, m, 64);
        if (l32 == 0)
            atomicAdd(&rowsum[rowBase + ms * 32 + (j & 3) + 8 * (j >> 2) + 4 * half], s);
    }
}

// ---- 3) loss = mean(log(rowsum) - pos), 1024 threads, float4 loads ----
__global__ __launch_bounds__(1024) void finalize_k(const float* __restrict__ rowsum,
                                                   const float* __restrict__ pos,
                                                   float* __restrict__ out) {
    __shared__ float red[16];
    const int t = threadIdx.x;
    const float4* rs4 = (const float4*)rowsum;
    const float4* ps4 = (const float4*)pos;
    float s = 0.f;
#pragma unroll
    for (int j = 0; j < 2; ++j) {
        float4 r = rs4[t * 2 + j];
        float4 p = ps4[t * 2 + j];
        s += (__logf(r.x) - p.x) + (__logf(r.y) - p.y) +
             (__logf(r.z) - p.z) + (__logf(r.w) - p.w);
    }
#pragma unroll
    for (int m = 1; m < 64; m <<= 1) s += __shfl_xor(s, m, 64);
    if ((t & 63) == 0) red[t >> 6] = s;
    __syncthreads();
    if (t == 0) {
        float tot = 0.f;
#pragma unroll
        for (int w = 0; w < 16; ++w) tot += red[w];
        out[0] = tot * (1.0f / (float)N_SZ);
    }
}

extern "C" void kernel_launch(void* const* d_in, const int* in_sizes, int n_in,
                              void* d_out, int out_size, void* d_ws, size_t ws_size,
                              hipStream_t stream) {
    const float* h1 = (const float*)d_in[0];
    const float* h2 = (const float*)d_in[1];
    float* out = (float*)d_out;

    char* ws = (char*)d_ws;
    unsigned char* hn8 = (unsigned char*)ws;                      // N*D = 6,291,456 B
    float* pos    = (float*)(ws + (size_t)N_SZ * D_SZ);            // 32 KB
    float* rowsum = (float*)(ws + (size_t)N_SZ * D_SZ + 32768);    // 32 KB

    prep_k<<<B_SZ / 4, 256, 0, stream>>>(h1, h2, hn8, pos, rowsum);
    const int nTiles = N_SZ / BN;                    // 64
    const int nBlocks = nTiles * (nTiles + 1) / 2;   // 2080
    gemm_reduce_k<<<nBlocks, 512, 0, stream>>>(hn8, rowsum);
    finalize_k<<<1, 1024, 0, stream>>>(rowsum, pos, out);
}